// Round 5
// baseline (441.320 us; speedup 1.0000x reference)
//
#include <hip/hip_runtime.h>
#include <hip/hip_bf16.h>

#define IN_FEAT 256
#define OUT_FEAT 32
#define RB 64            // rows per bucket
#define CAP 1280         // edge capacity per bucket (lambda=1024, +8 sigma)
#define OCAP 65536       // overflow list capacity
#define CNT_STRIDE 16    // u32 stride between counters -> 64B apart

typedef __attribute__((ext_vector_type(8))) short short8;
typedef __attribute__((ext_vector_type(4))) float f32x4;

__device__ __forceinline__ unsigned cvt_pk_bf16(float lo, float hi) {
    unsigned r;
    asm volatile("v_cvt_pk_bf16_f32 %0, %1, %2" : "=v"(r) : "v"(lo), "v"(hi));
    return r;
}

// ---------------------------------------------------------------------------
// Kernel 1: x = feat @ W via bf16 MFMA (measured 27 us in round 4, unchanged).
// ---------------------------------------------------------------------------
__global__ __launch_bounds__(256) void gemm_mfma_kernel(
    const float* __restrict__ feat,
    const float* __restrict__ W,
    float* __restrict__ x,
    int n)
{
    __shared__ short sWT[OUT_FEAT][IN_FEAT + 8];

    const int tid = threadIdx.x;
    for (int i = tid; i < IN_FEAT * OUT_FEAT; i += 256) {
        const int k = i >> 5, c = i & 31;
        __hip_bfloat16 h = __float2bfloat16(W[i]);
        sWT[c][k] = *reinterpret_cast<short*>(&h);
    }
    __syncthreads();

    const int wid  = tid >> 6;
    const int lane = tid & 63;
    const int tile = blockIdx.x * 4 + wid;
    const int row0 = tile * 16;
    if (row0 >= n) return;

    const int l16 = lane & 15;
    const int lh  = lane >> 4;

    if (row0 + 16 <= n) {
        const int row = row0 + l16;
        const float4* fr = reinterpret_cast<const float4*>(feat) + (size_t)row * (IN_FEAT / 4);

        float4 ra[8][2];
        #pragma unroll
        for (int ks = 0; ks < 8; ++ks) {
            ra[ks][0] = fr[ks * 8 + lh * 2];
            ra[ks][1] = fr[ks * 8 + lh * 2 + 1];
        }

        f32x4 acc0 = {0.f, 0.f, 0.f, 0.f};
        f32x4 acc1 = {0.f, 0.f, 0.f, 0.f};

        #pragma unroll
        for (int ks = 0; ks < 8; ++ks) {
            union { short8 s; unsigned u[4]; } af;
            af.u[0] = cvt_pk_bf16(ra[ks][0].x, ra[ks][0].y);
            af.u[1] = cvt_pk_bf16(ra[ks][0].z, ra[ks][0].w);
            af.u[2] = cvt_pk_bf16(ra[ks][1].x, ra[ks][1].y);
            af.u[3] = cvt_pk_bf16(ra[ks][1].z, ra[ks][1].w);

            const int k0 = ks * 32 + lh * 8;
            short8 b0 = *reinterpret_cast<const short8*>(&sWT[l16][k0]);
            short8 b1 = *reinterpret_cast<const short8*>(&sWT[16 + l16][k0]);

            acc0 = __builtin_amdgcn_mfma_f32_16x16x32_bf16(af.s, b0, acc0, 0, 0, 0);
            acc1 = __builtin_amdgcn_mfma_f32_16x16x32_bf16(af.s, b1, acc1, 0, 0, 0);
        }

        #pragma unroll
        for (int r = 0; r < 4; ++r) {
            const size_t orow = (size_t)(row0 + lh * 4 + r) * OUT_FEAT;
            x[orow + l16]      = acc0[r];
            x[orow + 16 + l16] = acc1[r];
        }
    } else {
        const int rows = n - row0;
        for (int idx = lane; idx < rows * OUT_FEAT; idx += 64) {
            const int r = idx >> 5, j = idx & 31;
            float a = 0.f;
            for (int k = 0; k < IN_FEAT; ++k) {
                unsigned wb = ((unsigned)(unsigned short)sWT[j][k]) << 16;
                a += feat[(size_t)(row0 + r) * IN_FEAT + k] * __uint_as_float(wb);
            }
            x[(size_t)(row0 + r) * OUT_FEAT + j] = a;
        }
    }
}

// ---------------------------------------------------------------------------
// Kernel 2: bin edges by row bucket (row>>6), 4 edges/thread vectorized.
//   Packed entry {key=(rlocal<<17)|col, val}. Global atomics: 1.6M (32x fewer
//   than flat scatter's 51.2M).
// ---------------------------------------------------------------------------
__global__ __launch_bounds__(256) void bin_kernel(
    const float* __restrict__ vals,
    const int* __restrict__ erow,
    const int* __restrict__ ecol,
    uint2* __restrict__ ebuf,
    unsigned* __restrict__ cnt,
    unsigned* __restrict__ ocnt,
    uint4* __restrict__ obuf,
    int n_edges)
{
    const int nq = n_edges >> 2;   // quads
    const int stride = gridDim.x * blockDim.x;
    for (int q = blockIdx.x * blockDim.x + threadIdx.x; q < nq; q += stride) {
        const int4   r4 = reinterpret_cast<const int4*>(erow)[q];
        const int4   c4 = reinterpret_cast<const int4*>(ecol)[q];
        const float4 v4 = reinterpret_cast<const float4*>(vals)[q];
        #pragma unroll
        for (int t = 0; t < 4; ++t) {
            const int r = (t == 0) ? r4.x : (t == 1) ? r4.y : (t == 2) ? r4.z : r4.w;
            const int c = (t == 0) ? c4.x : (t == 1) ? c4.y : (t == 2) ? c4.z : c4.w;
            const float v = (t == 0) ? v4.x : (t == 1) ? v4.y : (t == 2) ? v4.z : v4.w;
            const int b = r >> 6;
            unsigned pos = atomicAdd(&cnt[(size_t)b * CNT_STRIDE], 1u);
            if (pos < CAP) {
                ebuf[(size_t)b * CAP + pos] =
                    make_uint2(((unsigned)(r & 63) << 17) | (unsigned)c, __float_as_uint(v));
            } else {
                unsigned o = atomicAdd(ocnt, 1u);
                if (o < OCAP)
                    obuf[o] = make_uint4((unsigned)r, (unsigned)c, __float_as_uint(v), 0u);
            }
        }
    }
    // scalar tail (n_edges % 4, none for 1.6M)
    if (blockIdx.x == 0 && threadIdx.x < (n_edges & 3)) {
        const int e = nq * 4 + threadIdx.x;
        const int r = erow[e], c = ecol[e];
        const float v = vals[e];
        const int b = r >> 6;
        unsigned pos = atomicAdd(&cnt[(size_t)b * CNT_STRIDE], 1u);
        if (pos < CAP)
            ebuf[(size_t)b * CAP + pos] =
                make_uint2(((unsigned)(r & 63) << 17) | (unsigned)c, __float_as_uint(v));
        else {
            unsigned o = atomicAdd(ocnt, 1u);
            if (o < OCAP)
                obuf[o] = make_uint4((unsigned)r, (unsigned)c, __float_as_uint(v), 0u);
        }
    }
}

// ---------------------------------------------------------------------------
// Kernel 3: per-bucket SpMM, v2.
//   Round-2's consumer read entries via GLOBAL broadcast loads (16 B useful
//   per wave-instr — the round-3 poison). v2 stages entries into LDS
//   coalesced (distinct 8 B/lane, 512 B/instr), then inner loop:
//   LDS broadcast entry (free) + global x gather (2x128 B rows/instr,
//   4 independent chains) + LDS atomic (2-way bank alias = free).
//   Non-atomic full-coverage float4 out write.
//   LDS 18.25 KB -> 8 blocks/CU, 32 waves/CU.
// ---------------------------------------------------------------------------
__global__ __launch_bounds__(256) void spmm_bucket2_kernel(
    const uint2* __restrict__ ebuf,
    const unsigned* __restrict__ cnt,
    const float* __restrict__ x,
    float* __restrict__ out,
    int n_nodes)
{
    __shared__ float acc[RB * OUT_FEAT];   // 8 KB
    __shared__ uint2 se[CAP];              // 10.25 KB

    const int tid = threadIdx.x;
    const int b = blockIdx.x;

    int n = (int)cnt[(size_t)b * CNT_STRIDE];
    if (n > CAP) n = CAP;

    #pragma unroll
    for (int i = 0; i < 8; ++i) acc[tid + i * 256] = 0.0f;

    // Coalesced staging of bucket entries into LDS.
    const uint2* eb = ebuf + (size_t)b * CAP;
    for (int i = tid; i < n; i += 256) se[i] = eb[i];
    __syncthreads();

    const int g = tid >> 5;   // edge-group 0..7
    const int j = tid & 31;   // feature

    int i = g;
    for (; i + 24 < n; i += 32) {
        uint2 p0 = se[i];
        uint2 p1 = se[i + 8];
        uint2 p2 = se[i + 16];
        uint2 p3 = se[i + 24];
        float x0 = x[(size_t)(p0.x & 0x1FFFFu) * OUT_FEAT + j];
        float x1 = x[(size_t)(p1.x & 0x1FFFFu) * OUT_FEAT + j];
        float x2 = x[(size_t)(p2.x & 0x1FFFFu) * OUT_FEAT + j];
        float x3 = x[(size_t)(p3.x & 0x1FFFFu) * OUT_FEAT + j];
        atomicAdd(&acc[(p0.x >> 17) * OUT_FEAT + j], __uint_as_float(p0.y) * x0);
        atomicAdd(&acc[(p1.x >> 17) * OUT_FEAT + j], __uint_as_float(p1.y) * x1);
        atomicAdd(&acc[(p2.x >> 17) * OUT_FEAT + j], __uint_as_float(p2.y) * x2);
        atomicAdd(&acc[(p3.x >> 17) * OUT_FEAT + j], __uint_as_float(p3.y) * x3);
    }
    for (; i < n; i += 8) {
        uint2 p = se[i];
        float xv = x[(size_t)(p.x & 0x1FFFFu) * OUT_FEAT + j];
        atomicAdd(&acc[(p.x >> 17) * OUT_FEAT + j], __uint_as_float(p.y) * xv);
    }
    __syncthreads();

    // Full-coverage non-atomic write (no out memset needed on this path).
    int nrows = n_nodes - b * RB;
    if (nrows > RB) nrows = RB;
    const int valid = nrows * OUT_FEAT;
    float4* out4 = reinterpret_cast<float4*>(out + (size_t)b * RB * OUT_FEAT);
    const float4* a4 = reinterpret_cast<const float4*>(acc);
    if (tid * 4 < valid)         out4[tid]       = a4[tid];
    if ((tid + 256) * 4 < valid) out4[tid + 256] = a4[tid + 256];
}

// ---------------------------------------------------------------------------
// Kernel 4: overflow cleanup (expected zero work).
// ---------------------------------------------------------------------------
__global__ __launch_bounds__(256) void oflow_kernel(
    const uint4* __restrict__ obuf,
    const unsigned* __restrict__ ocnt,
    const float* __restrict__ x,
    float* __restrict__ out)
{
    unsigned n = *ocnt;
    if (n > OCAP) n = OCAP;
    const long long total = (long long)n * OUT_FEAT;
    const long long stride = (long long)gridDim.x * blockDim.x;
    for (long long idx = blockIdx.x * (long long)blockDim.x + threadIdx.x;
         idx < total; idx += stride) {
        const int e = (int)(idx >> 5), j = (int)(idx & 31);
        uint4 p = obuf[e];
        atomicAdd(&out[(size_t)p.x * OUT_FEAT + j],
                  __uint_as_float(p.z) * x[(size_t)p.y * OUT_FEAT + j]);
    }
}

// ---------------------------------------------------------------------------
// Fallback: flat atomic scatter (round-1, measured 171 us) if ws too small.
// ---------------------------------------------------------------------------
__global__ __launch_bounds__(256) void spmm_scatter_kernel(
    const float* __restrict__ vals,
    const int* __restrict__ erow,
    const int* __restrict__ ecol,
    const float* __restrict__ x,
    float* __restrict__ out,
    int n_edges)
{
    const long long idx = (long long)blockIdx.x * blockDim.x + threadIdx.x;
    const int e = (int)(idx >> 5);
    const int j = (int)(idx & 31);
    if (e >= n_edges) return;
    const float m = vals[e] * x[(size_t)ecol[e] * OUT_FEAT + j];
    atomicAdd(&out[(size_t)erow[e] * OUT_FEAT + j], m);
}

// ---------------------------------------------------------------------------
extern "C" void kernel_launch(void* const* d_in, const int* in_sizes, int n_in,
                              void* d_out, int out_size, void* d_ws, size_t ws_size,
                              hipStream_t stream)
{
    const float* feat = (const float*)d_in[0];
    const float* W    = (const float*)d_in[1];
    const float* vals = (const float*)d_in[2];
    const int*   erow = (const int*)d_in[3];
    const int*   ecol = (const int*)d_in[4];
    float* out = (float*)d_out;

    const int n_nodes = in_sizes[0] / IN_FEAT;
    const int n_edges = in_sizes[2];
    const int NB = (n_nodes + RB - 1) / RB;

    char* ws = (char*)d_ws;
    size_t off = 0;
    float* x = (float*)(ws + off);            off += (size_t)n_nodes * OUT_FEAT * sizeof(float);
    uint2* ebuf = (uint2*)(ws + off);         off += (size_t)NB * CAP * sizeof(uint2);
    unsigned* cnt = (unsigned*)(ws + off);    size_t cnt_off = off;
                                              off += (size_t)NB * CNT_STRIDE * sizeof(unsigned);
    unsigned* ocnt = (unsigned*)(ws + off);   off += 16;
    uint4* obuf = (uint4*)(ws + off);         off += (size_t)OCAP * sizeof(uint4);
    const bool bucketed = (ws_size >= off);

    // 1) x = feat @ W  (bf16 MFMA)
    {
        const int tiles = (n_nodes + 15) / 16;
        dim3 grid((tiles + 3) / 4);
        gemm_mfma_kernel<<<grid, 256, 0, stream>>>(feat, W, x, n_nodes);
    }

    if (bucketed) {
        size_t zlen = (size_t)NB * CNT_STRIDE * sizeof(unsigned) + 16;
        hipMemsetAsync(ws + cnt_off, 0, zlen, stream);

        bin_kernel<<<1024, 256, 0, stream>>>(vals, erow, ecol, ebuf, cnt, ocnt, obuf, n_edges);
        spmm_bucket2_kernel<<<NB, 256, 0, stream>>>(ebuf, cnt, x, out, n_nodes);
        oflow_kernel<<<64, 256, 0, stream>>>(obuf, ocnt, x, out);
    } else {
        hipMemsetAsync(d_out, 0, (size_t)out_size * sizeof(float), stream);
        long long total = (long long)n_edges * OUT_FEAT;
        spmm_scatter_kernel<<<(unsigned)((total + 255) / 256), 256, 0, stream>>>(
            vals, erow, ecol, x, out, n_edges);
    }
}

// Round 6
// 198.245 us; speedup vs baseline: 2.2261x; 2.2261x over previous
//
#include <hip/hip_runtime.h>
#include <hip/hip_bf16.h>

#define IN_FEAT 256
#define OUT_FEAT 32

// ---- two-level partition geometry ----
#define NC_MAX 128       // max coarse buckets supported (n_nodes <= 131072)
#define CAPC 17408       // capacity per coarse bucket (lambda~16327, +8.4 sigma); 256*68
#define L1_CHUNK 2048    // edges per part1 block (8 per thread)
#define NF 16            // fine buckets per coarse (64 rows each)
#define CAPF 1280        // capacity per fine bucket (lambda~1020, +8 sigma)
#define L2_SPLIT 8
#define L2_CHUNK (CAPC / L2_SPLIT)   // 2176 entries (9 per thread max)
#define OCAP 65536

typedef __attribute__((ext_vector_type(8))) short short8;
typedef __attribute__((ext_vector_type(4))) float f32x4;

__device__ __forceinline__ unsigned cvt_pk_bf16(float lo, float hi) {
    unsigned r;
    asm volatile("v_cvt_pk_bf16_f32 %0, %1, %2" : "=v"(r) : "v"(lo), "v"(hi));
    return r;
}

__device__ __forceinline__ void nt_store_f32(float* p, float v) {
    __builtin_nontemporal_store(v, p);
}
__device__ __forceinline__ void nt_store_u64(uint2* p, uint2 v) {
    __builtin_nontemporal_store(*reinterpret_cast<unsigned long long*>(&v),
                                reinterpret_cast<unsigned long long*>(p));
}

// ---------------------------------------------------------------------------
// Kernel 1: x = feat @ W via bf16 MFMA (27 us measured; x stores now NT to
// keep lines clean for cross-XCD random gathers in the consumer).
// ---------------------------------------------------------------------------
__global__ __launch_bounds__(256) void gemm_mfma_kernel(
    const float* __restrict__ feat,
    const float* __restrict__ W,
    float* __restrict__ x,
    int n)
{
    __shared__ short sWT[OUT_FEAT][IN_FEAT + 8];

    const int tid = threadIdx.x;
    for (int i = tid; i < IN_FEAT * OUT_FEAT; i += 256) {
        const int k = i >> 5, c = i & 31;
        __hip_bfloat16 h = __float2bfloat16(W[i]);
        sWT[c][k] = *reinterpret_cast<short*>(&h);
    }
    __syncthreads();

    const int wid  = tid >> 6;
    const int lane = tid & 63;
    const int tile = blockIdx.x * 4 + wid;
    const int row0 = tile * 16;
    if (row0 >= n) return;

    const int l16 = lane & 15;
    const int lh  = lane >> 4;

    if (row0 + 16 <= n) {
        const int row = row0 + l16;
        const float4* fr = reinterpret_cast<const float4*>(feat) + (size_t)row * (IN_FEAT / 4);

        float4 ra[8][2];
        #pragma unroll
        for (int ks = 0; ks < 8; ++ks) {
            ra[ks][0] = fr[ks * 8 + lh * 2];
            ra[ks][1] = fr[ks * 8 + lh * 2 + 1];
        }

        f32x4 acc0 = {0.f, 0.f, 0.f, 0.f};
        f32x4 acc1 = {0.f, 0.f, 0.f, 0.f};

        #pragma unroll
        for (int ks = 0; ks < 8; ++ks) {
            union { short8 s; unsigned u[4]; } af;
            af.u[0] = cvt_pk_bf16(ra[ks][0].x, ra[ks][0].y);
            af.u[1] = cvt_pk_bf16(ra[ks][0].z, ra[ks][0].w);
            af.u[2] = cvt_pk_bf16(ra[ks][1].x, ra[ks][1].y);
            af.u[3] = cvt_pk_bf16(ra[ks][1].z, ra[ks][1].w);

            const int k0 = ks * 32 + lh * 8;
            short8 b0 = *reinterpret_cast<const short8*>(&sWT[l16][k0]);
            short8 b1 = *reinterpret_cast<const short8*>(&sWT[16 + l16][k0]);

            acc0 = __builtin_amdgcn_mfma_f32_16x16x32_bf16(af.s, b0, acc0, 0, 0, 0);
            acc1 = __builtin_amdgcn_mfma_f32_16x16x32_bf16(af.s, b1, acc1, 0, 0, 0);
        }

        #pragma unroll
        for (int r = 0; r < 4; ++r) {
            const size_t orow = (size_t)(row0 + lh * 4 + r) * OUT_FEAT;
            nt_store_f32(&x[orow + l16],      acc0[r]);
            nt_store_f32(&x[orow + 16 + l16], acc1[r]);
        }
    } else {
        const int rows = n - row0;
        for (int idx = lane; idx < rows * OUT_FEAT; idx += 64) {
            const int r = idx >> 5, j = idx & 31;
            float a = 0.f;
            for (int k = 0; k < IN_FEAT; ++k) {
                unsigned wb = ((unsigned)(unsigned short)sWT[j][k]) << 16;
                a += feat[(size_t)(row0 + r) * IN_FEAT + k] * __uint_as_float(wb);
            }
            x[(size_t)(row0 + r) * OUT_FEAT + j] = a;
        }
    }
}

// ---------------------------------------------------------------------------
// Kernel 2: level-1 partition into coarse buckets (row>>10), LDS-staged so
//   global writes are bucket-sorted runs (~21 entries), line-granular.
//   Entry: {meta = (row&1023)<<17 | col, valbits}. ~98 global atomics/block.
// ---------------------------------------------------------------------------
__global__ __launch_bounds__(256) void part1_kernel(
    const float* __restrict__ vals,
    const int* __restrict__ erow,
    const int* __restrict__ ecol,
    uint2* __restrict__ buf1,
    unsigned* __restrict__ cnt1,
    unsigned* __restrict__ ocnt,
    uint4* __restrict__ obuf,
    int n_edges, int nc)
{
    __shared__ uint2 sE[L1_CHUNK];              // 16 KB
    __shared__ unsigned char sBkt[L1_CHUNK];    // 2 KB
    __shared__ unsigned sHist[NC_MAX], sBase[NC_MAX], sCur[NC_MAX], sGBase[NC_MAX];

    const int tid = threadIdx.x;
    const int chunk0 = blockIdx.x * L1_CHUNK;
    const int nq = n_edges >> 2;

    for (int b = tid; b < nc; b += 256) { sHist[b] = 0; sCur[b] = 0; }
    __syncthreads();

    // 8 edges per thread in registers (2x int4 + 2x float4 vectorized loads)
    int4 r4[2]; int4 c4[2]; float4 v4[2];
    #pragma unroll
    for (int i = 0; i < 2; ++i) {
        const int qi = (chunk0 >> 2) + tid + i * 256;
        if (qi < nq) {
            r4[i] = reinterpret_cast<const int4*>(erow)[qi];
            c4[i] = reinterpret_cast<const int4*>(ecol)[qi];
            v4[i] = reinterpret_cast<const float4*>(vals)[qi];
        } else {
            r4[i] = make_int4(-1, -1, -1, -1);
            c4[i] = make_int4(0, 0, 0, 0);
            v4[i] = make_float4(0.f, 0.f, 0.f, 0.f);
        }
    }

    // histogram
    #pragma unroll
    for (int i = 0; i < 2; ++i) {
        const int* rr = &r4[i].x;
        #pragma unroll
        for (int t = 0; t < 4; ++t)
            if (rr[t] >= 0) atomicAdd(&sHist[rr[t] >> 10], 1u);
    }
    __syncthreads();

    // exclusive prefix (thread 0; nc<=128, short dependent chain)
    if (tid == 0) {
        unsigned s = 0;
        for (int b = 0; b < nc; ++b) { sBase[b] = s; s += sHist[b]; }
    }
    __syncthreads();

    // reserve global ranges
    for (int b = tid; b < nc; b += 256)
        sGBase[b] = atomicAdd(&cnt1[b], sHist[b]);
    __syncthreads();

    // place entries bucket-sorted in LDS
    #pragma unroll
    for (int i = 0; i < 2; ++i) {
        const int*   rr = &r4[i].x;
        const int*   cc = &c4[i].x;
        const float* vv = &v4[i].x;
        #pragma unroll
        for (int t = 0; t < 4; ++t) {
            const int r = rr[t];
            if (r >= 0) {
                const int cb = r >> 10;
                unsigned p = sBase[cb] + atomicAdd(&sCur[cb], 1u);
                sE[p] = make_uint2(((unsigned)(r & 1023) << 17) | (unsigned)cc[t],
                                   __float_as_uint(vv[t]));
                sBkt[p] = (unsigned char)cb;
            }
        }
    }
    __syncthreads();

    // coalesced copy-out (runs of same bucket -> consecutive global addrs)
    int total = n_edges - chunk0;
    if (total > L1_CHUNK) total = L1_CHUNK;
    for (int p = tid; p < total; p += 256) {
        const int cb = sBkt[p];
        const unsigned g = sGBase[cb] + (p - sBase[cb]);
        const uint2 e = sE[p];
        if (g < CAPC) {
            nt_store_u64(&buf1[(size_t)cb * CAPC + g], e);
        } else {
            unsigned o = atomicAdd(ocnt, 1u);
            if (o < OCAP)
                obuf[o] = make_uint4(((unsigned)cb << 10) | (e.x >> 17),
                                     e.x & 0x1FFFFu, e.y, 0u);
        }
    }

    // scalar tail for n_edges % 4 (none for 1.6M): route via overflow list
    if (blockIdx.x == 0 && tid < (n_edges & 3)) {
        const int e = (nq << 2) + tid;
        unsigned o = atomicAdd(ocnt, 1u);
        if (o < OCAP)
            obuf[o] = make_uint4((unsigned)erow[e], (unsigned)ecol[e],
                                 __float_as_uint(vals[e]), 0u);
    }
}

// ---------------------------------------------------------------------------
// Kernel 3: level-2 partition: each coarse bucket -> 16 fine buckets of 64
//   rows (key = meta>>23). Fully coalesced reads; writes in runs ~136 entries.
// ---------------------------------------------------------------------------
__global__ __launch_bounds__(256) void part2_kernel(
    const uint2* __restrict__ buf1,
    const unsigned* __restrict__ cnt1,
    uint2* __restrict__ buf2,
    unsigned* __restrict__ cnt2,
    unsigned* __restrict__ ocnt,
    uint4* __restrict__ obuf)
{
    __shared__ uint2 sE[L2_CHUNK];              // 17 KB
    __shared__ unsigned char sBkt[L2_CHUNK];    // 2.1 KB
    __shared__ unsigned sHist[NF], sBase[NF], sCur[NF], sGBase[NF];

    const int tid = threadIdx.x;
    const int cb = blockIdx.x / L2_SPLIT;
    const int s  = blockIdx.x % L2_SPLIT;

    unsigned n1 = cnt1[cb]; if (n1 > CAPC) n1 = CAPC;
    const int i0 = s * L2_CHUNK;
    int cnt = (int)n1 - i0;
    if (cnt < 0) cnt = 0;
    if (cnt > L2_CHUNK) cnt = L2_CHUNK;

    if (tid < NF) { sHist[tid] = 0; sCur[tid] = 0; }
    __syncthreads();

    uint2 ent[9];
    #pragma unroll
    for (int i = 0; i < 9; ++i) {
        const int p = tid + i * 256;
        ent[i] = (p < cnt) ? buf1[(size_t)cb * CAPC + i0 + p]
                           : make_uint2(0xFFFFFFFFu, 0u);   // valid meta < 2^27
    }
    #pragma unroll
    for (int i = 0; i < 9; ++i)
        if (ent[i].x != 0xFFFFFFFFu) atomicAdd(&sHist[ent[i].x >> 23], 1u);
    __syncthreads();

    if (tid == 0) {
        unsigned acc = 0;
        for (int b = 0; b < NF; ++b) { sBase[b] = acc; acc += sHist[b]; }
    }
    __syncthreads();
    if (tid < NF) sGBase[tid] = atomicAdd(&cnt2[cb * NF + tid], sHist[tid]);
    __syncthreads();

    #pragma unroll
    for (int i = 0; i < 9; ++i) {
        if (ent[i].x != 0xFFFFFFFFu) {
            const int f = ent[i].x >> 23;
            unsigned p = sBase[f] + atomicAdd(&sCur[f], 1u);
            sE[p] = ent[i];
            sBkt[p] = (unsigned char)f;
        }
    }
    __syncthreads();

    for (int p = tid; p < cnt; p += 256) {
        const int f = sBkt[p];
        const unsigned g = sGBase[f] + (p - sBase[f]);
        const uint2 e = sE[p];
        if (g < CAPF) {
            nt_store_u64(&buf2[((size_t)cb * NF + f) * CAPF + g], e);
        } else {
            unsigned o = atomicAdd(ocnt, 1u);
            if (o < OCAP)
                obuf[o] = make_uint4(((unsigned)cb << 10) | (e.x >> 17),
                                     e.x & 0x1FFFFu, e.y, 0u);
        }
    }
}

// ---------------------------------------------------------------------------
// Kernel 4: consumer. One block per fine bucket (64 rows), 1024 threads =
//   32 groups of 32 lanes; n~1020 edges -> only 4 outer iterations of an
//   8-wide unroll (8 independent gathers in flight). LDS acc conflict-free.
//   Non-atomic full-coverage out write (no memset needed).
// ---------------------------------------------------------------------------
__global__ __launch_bounds__(1024) void spmm_consumer_kernel(
    const uint2* __restrict__ buf2,
    const unsigned* __restrict__ cnt2,
    const float* __restrict__ x,
    float* __restrict__ out,
    int n_nodes)
{
    __shared__ float acc[64 * OUT_FEAT];   // 8 KB
    __shared__ uint2 se[CAPF];             // 10.25 KB

    const int tid = threadIdx.x;
    const int fb = blockIdx.x;

    unsigned n = cnt2[fb]; if (n > CAPF) n = CAPF;

    acc[tid] = 0.f; acc[tid + 1024] = 0.f;
    const uint2* eb = buf2 + (size_t)fb * CAPF;
    if (tid < n) se[tid] = eb[tid];
    if (tid + 1024 < n) se[tid + 1024] = eb[tid + 1024];
    __syncthreads();

    const int g = tid >> 5;   // 0..31
    const int j = tid & 31;

    int i = g;
    for (; i + 224 < (int)n; i += 256) {
        uint2 p[8];
        float xv[8];
        #pragma unroll
        for (int k = 0; k < 8; ++k) p[k] = se[i + 32 * k];
        #pragma unroll
        for (int k = 0; k < 8; ++k)
            xv[k] = x[(size_t)(p[k].x & 0x1FFFFu) * OUT_FEAT + j];
        #pragma unroll
        for (int k = 0; k < 8; ++k)
            atomicAdd(&acc[((p[k].x >> 17) & 63u) * OUT_FEAT + j],
                      __uint_as_float(p[k].y) * xv[k]);
    }
    for (; i < (int)n; i += 32) {
        const uint2 p = se[i];
        const float xv = x[(size_t)(p.x & 0x1FFFFu) * OUT_FEAT + j];
        atomicAdd(&acc[((p.x >> 17) & 63u) * OUT_FEAT + j],
                  __uint_as_float(p.y) * xv);
    }
    __syncthreads();

    int valid = (n_nodes - fb * 64) * OUT_FEAT;
    if (valid > 64 * OUT_FEAT) valid = 64 * OUT_FEAT;
    if (valid > 0 && tid * 4 < valid) {
        reinterpret_cast<float4*>(out + (size_t)fb * 64 * OUT_FEAT)[tid] =
            reinterpret_cast<const float4*>(acc)[tid];
    }
}

// ---------------------------------------------------------------------------
// Kernel 5: overflow cleanup (expected zero work). Runs after consumer.
// ---------------------------------------------------------------------------
__global__ __launch_bounds__(256) void oflow_kernel(
    const uint4* __restrict__ obuf,
    const unsigned* __restrict__ ocnt,
    const float* __restrict__ x,
    float* __restrict__ out)
{
    unsigned n = *ocnt;
    if (n > OCAP) n = OCAP;
    const long long total = (long long)n * OUT_FEAT;
    const long long stride = (long long)gridDim.x * blockDim.x;
    for (long long idx = blockIdx.x * (long long)blockDim.x + threadIdx.x;
         idx < total; idx += stride) {
        const int e = (int)(idx >> 5), j = (int)(idx & 31);
        uint4 p = obuf[e];
        atomicAdd(&out[(size_t)p.x * OUT_FEAT + j],
                  __uint_as_float(p.z) * x[(size_t)p.y * OUT_FEAT + j]);
    }
}

// ---------------------------------------------------------------------------
// Fallback: flat atomic scatter (measured 171 us) if ws too small / shape odd.
// ---------------------------------------------------------------------------
__global__ __launch_bounds__(256) void spmm_scatter_kernel(
    const float* __restrict__ vals,
    const int* __restrict__ erow,
    const int* __restrict__ ecol,
    const float* __restrict__ x,
    float* __restrict__ out,
    int n_edges)
{
    const long long idx = (long long)blockIdx.x * blockDim.x + threadIdx.x;
    const int e = (int)(idx >> 5);
    const int j = (int)(idx & 31);
    if (e >= n_edges) return;
    const float m = vals[e] * x[(size_t)ecol[e] * OUT_FEAT + j];
    atomicAdd(&out[(size_t)erow[e] * OUT_FEAT + j], m);
}

// ---------------------------------------------------------------------------
extern "C" void kernel_launch(void* const* d_in, const int* in_sizes, int n_in,
                              void* d_out, int out_size, void* d_ws, size_t ws_size,
                              hipStream_t stream)
{
    const float* feat = (const float*)d_in[0];
    const float* W    = (const float*)d_in[1];
    const float* vals = (const float*)d_in[2];
    const int*   erow = (const int*)d_in[3];
    const int*   ecol = (const int*)d_in[4];
    float* out = (float*)d_out;

    const int n_nodes = in_sizes[0] / IN_FEAT;
    const int n_edges = in_sizes[2];
    const int nc  = (n_nodes + 1023) >> 10;       // coarse buckets
    const int nfb = nc * NF;                      // fine buckets

    // workspace layout (16B-aligned segments)
    char* ws = (char*)d_ws;
    size_t off = 0;
    auto alloc = [&](size_t bytes) { size_t o = off; off = (off + bytes + 15) & ~(size_t)15; return o; };
    float*    x    = (float*)(ws + alloc((size_t)n_nodes * OUT_FEAT * sizeof(float)));
    uint2*    buf1 = (uint2*)(ws + alloc((size_t)nc * CAPC * sizeof(uint2)));
    uint2*    buf2 = (uint2*)(ws + alloc((size_t)nfb * CAPF * sizeof(uint2)));
    size_t cnt_off = off;
    unsigned* cnt1 = (unsigned*)(ws + alloc((size_t)nc * sizeof(unsigned)));
    unsigned* cnt2 = (unsigned*)(ws + alloc((size_t)nfb * sizeof(unsigned)));
    unsigned* ocnt = (unsigned*)(ws + alloc(sizeof(unsigned)));
    size_t cnt_end = (size_t)((char*)ocnt - ws) + sizeof(unsigned);
    uint4*    obuf = (uint4*)(ws + alloc((size_t)OCAP * sizeof(uint4)));

    const bool sorted_path = (ws_size >= off) && (nc <= NC_MAX) &&
                             (n_edges / (nc > 0 ? nc : 1) <= CAPC / 2);

    // 1) x = feat @ W  (bf16 MFMA)
    {
        const int tiles = (n_nodes + 15) / 16;
        dim3 grid((tiles + 3) / 4);
        gemm_mfma_kernel<<<grid, 256, 0, stream>>>(feat, W, x, n_nodes);
    }

    if (sorted_path) {
        // zero cnt1 + cnt2 + ocnt (contiguous)
        hipMemsetAsync(ws + cnt_off, 0, cnt_end - cnt_off, stream);

        // 2) level-1 partition (coarse buckets of 1024 rows)
        {
            const int nblk = (n_edges + L1_CHUNK - 1) / L1_CHUNK;
            part1_kernel<<<nblk, 256, 0, stream>>>(vals, erow, ecol, buf1, cnt1,
                                                   ocnt, obuf, n_edges, nc);
        }
        // 3) level-2 partition (fine buckets of 64 rows)
        part2_kernel<<<nc * L2_SPLIT, 256, 0, stream>>>(buf1, cnt1, buf2, cnt2,
                                                        ocnt, obuf);
        // 4) consumer: LDS accumulate per fine bucket, coalesced out write
        spmm_consumer_kernel<<<nfb, 1024, 0, stream>>>(buf2, cnt2, x, out, n_nodes);
        // 5) overflow cleanup (expected empty)
        oflow_kernel<<<64, 256, 0, stream>>>(obuf, ocnt, x, out);
    } else {
        hipMemsetAsync(d_out, 0, (size_t)out_size * sizeof(float), stream);
        long long total = (long long)n_edges * OUT_FEAT;
        spmm_scatter_kernel<<<(unsigned)((total + 255) / 256), 256, 0, stream>>>(
            vals, erow, ecol, x, out, n_edges);
    }
}